// Round 8
// baseline (240.079 us; speedup 1.0000x reference)
//
#include <hip/hip_runtime.h>
#include <hip/hip_bf16.h>
#include <cstdint>
#include <cstddef>

// Problem constants
#define BDIM   32768
#define KDIM   2048
#define NDIM   128
#define VHEADS 20
#define PDIM   6
#define RLORA  10

#define BM     16
#define BK     64
#define NCH    (KDIM / BK)                  // 32
#define OUT_ELEMS   (BDIM * VHEADS * PDIM)  // 3932160
#define WS_W_BYTES  (KDIM * NDIM * 2)       // 524288

typedef __attribute__((ext_vector_type(8))) __bf16 bf16x8;
typedef __attribute__((ext_vector_type(4))) float f32x4;
typedef __attribute__((ext_vector_type(2))) float f32x2;
typedef __attribute__((ext_vector_type(4))) unsigned int u32x4;

union FragU { bf16x8 b; u32x4 u; };

__device__ __forceinline__ unsigned int cvt_pk_bf16(float lo, float hi) {
  unsigned int r;
  asm("v_cvt_pk_bf16_f32 %0, %1, %2" : "=v"(r) : "v"(lo), "v"(hi));
  return r;
}

__device__ __forceinline__ float fast_tanh(float x) {
  float ax = fabsf(x);
  float e  = __expf(-2.0f * ax);
  float t  = __fdividef(1.0f - e, 1.0f + e);
  return copysignf(t, x);
}

// ---------------------------------------------------------------------------
// k0: pack We1 f32[2048][128] -> bf16 in B-FRAGMENT-MAJOR order:
//   n = nt*16 + (lane&15), k = c*64 + ks*32 + (lane>>4)*8 + j.
//   B-load for (c,nt,ks) = one dwordx4 at wp + (c*16+nt*2+ks)*1024 + lane*16.
// Also M = lora_A @ lora_B ([2][120]).
// ---------------------------------------------------------------------------
__global__ __launch_bounds__(256)
void k0_pack(const float* __restrict__ We1,
             const float* __restrict__ lA,
             const float* __restrict__ lB,
             unsigned short* __restrict__ wsw,
             float* __restrict__ wsM) {
  if (blockIdx.x == 128) {
    int t = threadIdx.x;
    if (t < 2 * VHEADS * PDIM) {
      int d  = t / (VHEADS * PDIM);
      int vp = t - d * (VHEADS * PDIM);
      float s = 0.f;
#pragma unroll
      for (int r = 0; r < RLORA; ++r)
        s = fmaf(lA[d * RLORA + r], lB[r * (VHEADS * PDIM) + vp], s);
      wsM[t] = s;  // layout [d][vp]
    }
    return;
  }
  int t    = blockIdx.x * 256 + threadIdx.x;  // 0..32767
  int lane = t & 63;
  int blk  = t >> 6;                          // 0..511
  int ks   = blk & 1;
  int nt   = (blk >> 1) & 7;
  int c    = blk >> 4;
  int n    = nt * 16 + (lane & 15);
  int kb   = c * 64 + ks * 32 + (lane >> 4) * 8;

  unsigned int u[4];
#pragma unroll
  for (int q = 0; q < 4; ++q) {
    float f0 = We1[(size_t)(kb + 2 * q + 0) * NDIM + n];
    float f1 = We1[(size_t)(kb + 2 * q + 1) * NDIM + n];
    __hip_bfloat16 h0 = __float2bfloat16(f0);
    __hip_bfloat16 h1 = __float2bfloat16(f1);
    u[q] = (unsigned int)*reinterpret_cast<unsigned short*>(&h0) |
           ((unsigned int)*reinterpret_cast<unsigned short*>(&h1) << 16);
  }
  *reinterpret_cast<u32x4*>(wsw + (size_t)t * 8) = u32x4{u[0], u[1], u[2], u[3]};
}

// ---------------------------------------------------------------------------
// k1: fused encoder + heads — BARRIER-FREE main loop, occupancy-driven.
//   2048 blocks x 256 thr (4 waves).  BM=16 rows/block; all 4 waves compute
//   the SAME 16 rows, wave wv owns cols [wv*32, wv*32+32) (nt = wv*2, wv*2+1).
//   Per chunk (BK=64): A = 4 dwordx4 f32 direct from global (pipelined one
//   chunk ahead, regs); B = 4 dwordx4 from the L2-resident fragment pack.
//   cvt_pk -> bf16 frags -> 4 MFMA.  NO LDS, NO __syncthreads in the loop:
//   nothing forces vmcnt(0); latency hidden by ~20 waves/CU x MLP>=8.
//   A lines shared by sibling waves via L1/L2 (so no nontemporal on A).
//   Epilogue: be1/relu/We2 partials, shfl-reduce, tiny LDS cross-wave
//   z-reduce (2 barriers total), then fused heads.
// ---------------------------------------------------------------------------
__global__ __launch_bounds__(256, 4)
void k1_fused(const float* __restrict__ x,
              const unsigned short* __restrict__ wp,
              const float* __restrict__ be1,
              const float* __restrict__ We2,
              const float* __restrict__ be2,
              const float* __restrict__ W1,
              const float* __restrict__ b1,
              const float* __restrict__ W2,
              const float* __restrict__ b2,
              const float* __restrict__ M,
              float* __restrict__ out,
              float* __restrict__ zout) {
  __shared__ float zpart[4][16][2];
  __shared__ float zsh[16][2];

  const int tid  = threadIdx.x;
  const int lane = tid & 63;
  const int wv   = tid >> 6;   // 0..3  (column group)
  const int l15  = lane & 15;
  const int kgrp = lane >> 4;  // 0..3
  const int blk  = blockIdx.x;

  // A: row = blk*16 + l15, k base = kgrp*8
  const float* aptr = x + (size_t)(blk * BM + l15) * KDIM + kgrp * 8;
  // B: this wave's two n-tiles, fragment-packed
  const char* bptr = (const char*)wp + lane * 16;

  f32x4 acc[2];
  acc[0] = f32x4{0.f, 0.f, 0.f, 0.f};
  acc[1] = f32x4{0.f, 0.f, 0.f, 0.f};

  f32x4 A0[4], A1[4];

  auto LOADA = [&](f32x4* A, int c) {
    const float* p = aptr + c * BK;
    A[0] = *(const f32x4*)(p);
    A[1] = *(const f32x4*)(p + 4);
    A[2] = *(const f32x4*)(p + 32);
    A[3] = *(const f32x4*)(p + 36);
  };

  auto STEP = [&](const f32x4* A, int c) {
    // B fragments for this wave's 2 n-tiles, both K-halves (L2-hot)
    const char* bc = bptr + (size_t)c * 16384;
    FragU b00, b01, b10, b11;
    b00.u = *(const u32x4*)(bc + ((wv * 2 + 0) * 2 + 0) * 1024);
    b01.u = *(const u32x4*)(bc + ((wv * 2 + 0) * 2 + 1) * 1024);
    b10.u = *(const u32x4*)(bc + ((wv * 2 + 1) * 2 + 0) * 1024);
    b11.u = *(const u32x4*)(bc + ((wv * 2 + 1) * 2 + 1) * 1024);
    FragU a0, a1;
    a0.u = u32x4{cvt_pk_bf16(A[0].x, A[0].y), cvt_pk_bf16(A[0].z, A[0].w),
                 cvt_pk_bf16(A[1].x, A[1].y), cvt_pk_bf16(A[1].z, A[1].w)};
    a1.u = u32x4{cvt_pk_bf16(A[2].x, A[2].y), cvt_pk_bf16(A[2].z, A[2].w),
                 cvt_pk_bf16(A[3].x, A[3].y), cvt_pk_bf16(A[3].z, A[3].w)};
    acc[0] = __builtin_amdgcn_mfma_f32_16x16x32_bf16(a0.b, b00.b, acc[0], 0, 0, 0);
    acc[0] = __builtin_amdgcn_mfma_f32_16x16x32_bf16(a1.b, b01.b, acc[0], 0, 0, 0);
    acc[1] = __builtin_amdgcn_mfma_f32_16x16x32_bf16(a0.b, b10.b, acc[1], 0, 0, 0);
    acc[1] = __builtin_amdgcn_mfma_f32_16x16x32_bf16(a1.b, b11.b, acc[1], 0, 0, 0);
  };

  // software pipeline: A one chunk ahead (unroll 2 keeps indices static)
  LOADA(A0, 0);
#pragma unroll 1
  for (int c = 0; c < NCH; c += 2) {
    if (c + 1 < NCH) LOADA(A1, c + 1);
    STEP(A0, c);
    if (c + 2 < NCH) LOADA(A0, c + 2);
    if (c + 1 < NCH) STEP(A1, c + 1);
  }

  // ---- epilogue: +be1, relu, @We2 partials (this wave's 32 cols)
  float part[4][2];
#pragma unroll
  for (int j = 0; j < 4; ++j) { part[j][0] = 0.f; part[j][1] = 0.f; }
#pragma unroll
  for (int ntl = 0; ntl < 2; ++ntl) {
    int col = (wv * 2 + ntl) * 16 + l15;
    float bb = be1[col];
    float w0 = We2[col * 2 + 0];
    float w1 = We2[col * 2 + 1];
#pragma unroll
    for (int j = 0; j < 4; ++j) {
      float h = acc[ntl][j] + bb;
      h = h > 0.f ? h : 0.f;
      part[j][0] = fmaf(h, w0, part[j][0]);
      part[j][1] = fmaf(h, w1, part[j][1]);
    }
  }
#pragma unroll
  for (int m = 1; m < 16; m <<= 1) {
#pragma unroll
    for (int j = 0; j < 4; ++j) {
      part[j][0] += __shfl_xor(part[j][0], m, 64);
      part[j][1] += __shfl_xor(part[j][1], m, 64);
    }
  }
  if (l15 == 0) {
#pragma unroll
    for (int j = 0; j < 4; ++j) {
      zpart[wv][kgrp * 4 + j][0] = part[j][0];
      zpart[wv][kgrp * 4 + j][1] = part[j][1];
    }
  }
  __syncthreads();
  if (tid < BM) {
    float s0 = zpart[0][tid][0] + zpart[1][tid][0] + zpart[2][tid][0] +
               zpart[3][tid][0] + be2[0];
    float s1 = zpart[0][tid][1] + zpart[1][tid][1] + zpart[2][tid][1] +
               zpart[3][tid][1] + be2[1];
    zsh[tid][0] = s0;
    zsh[tid][1] = s1;
    f32x2 zz = {s0, s1};
    *(f32x2*)(zout + (size_t)(blk * BM + tid) * 2) = zz;
  }
  __syncthreads();

  // ---- heads: row = tid&15, head slot = tid>>4 (slots 0..15; 0..3 also 16..19)
  const int srow = tid & 15;
  const int slot = tid >> 4;
  float z0 = zsh[srow][0];
  float z1 = zsh[srow][1];
  float* orow = out + (size_t)(blk * BM + srow) * (VHEADS * PDIM);

  auto head = [&](int v) {
    const float* w1a = W1 + (size_t)(v * 2 + 0) * NDIM;
    const float* w1b = W1 + (size_t)(v * 2 + 1) * NDIM;
    const float* bb1 = b1 + (size_t)v * NDIM;
    const float* w2  = W2 + (size_t)v * NDIM * PDIM;

    float p[6] = {0.f, 0.f, 0.f, 0.f, 0.f, 0.f};
#pragma unroll 4
    for (int h = 0; h < NDIM; ++h) {
      float hv = fmaf(z0, w1a[h], fmaf(z1, w1b[h], bb1[h]));
      hv = hv > 0.f ? hv : 0.f;
#pragma unroll
      for (int j = 0; j < 6; ++j) p[j] = fmaf(hv, w2[h * 6 + j], p[j]);
    }
    float o[6];
#pragma unroll
    for (int j = 0; j < 6; ++j) {
      float t1 = fast_tanh(p[j] + b2[v * PDIM + j]);
      float lo = fmaf(z0, M[v * PDIM + j], z1 * M[VHEADS * PDIM + v * PDIM + j]);
      o[j] = fast_tanh(fmaf(0.15f, lo, t1));
    }
    float* op = orow + v * PDIM;
    f32x2 o01 = {o[0], o[1]};
    f32x2 o23 = {o[2], o[3]};
    f32x2 o45 = {o[4], o[5]};
    __builtin_nontemporal_store(o01, (f32x2*)(op + 0));
    __builtin_nontemporal_store(o23, (f32x2*)(op + 2));
    __builtin_nontemporal_store(o45, (f32x2*)(op + 4));
  };

  head(slot);
  if (slot < 4) head(16 + slot);
}

// ---------------------------------------------------------------------------
extern "C" void kernel_launch(void* const* d_in, const int* in_sizes, int n_in,
                              void* d_out, int out_size, void* d_ws, size_t ws_size,
                              hipStream_t stream) {
  const float* x   = (const float*)d_in[0];
  const float* We1 = (const float*)d_in[1];
  const float* be1 = (const float*)d_in[2];
  const float* We2 = (const float*)d_in[3];
  const float* be2 = (const float*)d_in[4];
  const float* W1  = (const float*)d_in[5];
  const float* b1  = (const float*)d_in[6];
  const float* W2  = (const float*)d_in[7];
  const float* b2  = (const float*)d_in[8];
  const float* lA  = (const float*)d_in[9];
  const float* lB  = (const float*)d_in[10];

  float* out  = (float*)d_out;
  float* zout = out + OUT_ELEMS;                       // second tuple output
  unsigned short* wsw = (unsigned short*)d_ws;         // 512 KB bf16 W pack
  float* wsM = (float*)((char*)d_ws + WS_W_BYTES);     // 240 floats

  hipLaunchKernelGGL(k0_pack, dim3(129), dim3(256), 0, stream,
                     We1, lA, lB, wsw, wsM);
  hipLaunchKernelGGL(k1_fused, dim3(BDIM / BM), dim3(256), 0, stream,
                     x, wsw, be1, We2, be2, W1, b1, W2, b2, wsM, out, zout);
}

// Round 9
// 119.450 us; speedup vs baseline: 2.0099x; 2.0099x over previous
//
#include <hip/hip_runtime.h>
#include <hip/hip_bf16.h>
#include <cstdint>
#include <cstddef>

// Problem constants
#define BDIM   32768
#define KDIM   2048
#define NDIM   128
#define VHEADS 20
#define PDIM   6
#define RLORA  10

#define BK      64
#define NCHUNK  (KDIM / BK)                 // 32
#define OUT_ELEMS   (BDIM * VHEADS * PDIM)  // 3932160
#define WS_W_BYTES  (KDIM * NDIM * 2)       // 524288

typedef __attribute__((ext_vector_type(8))) __bf16 bf16x8;
typedef __attribute__((ext_vector_type(4))) float f32x4;
typedef __attribute__((ext_vector_type(2))) float f32x2;
typedef __attribute__((ext_vector_type(4))) unsigned int u32x4;

union FragU { bf16x8 b; u32x4 u; };

__device__ __forceinline__ unsigned int cvt_pk_bf16(float lo, float hi) {
  unsigned int r;
  asm("v_cvt_pk_bf16_f32 %0, %1, %2" : "=v"(r) : "v"(lo), "v"(hi));
  return r;
}

__device__ __forceinline__ void gload_lds16(const void* g, void* l) {
  __builtin_amdgcn_global_load_lds(
      (const __attribute__((address_space(1))) void*)(g),
      (__attribute__((address_space(3))) void*)(l), 16, 0, 0);
}

__device__ __forceinline__ float fast_tanh(float x) {
  float ax = fabsf(x);
  float e  = __expf(-2.0f * ax);
  float t  = __fdividef(1.0f - e, 1.0f + e);
  return copysignf(t, x);
}

// ---------------------------------------------------------------------------
// k0: pack We1 f32[2048][128] -> bf16 in B-FRAGMENT-MAJOR order:
//   n = nt*16 + (lane&15), k = c*64 + ks*32 + (lane>>4)*8 + j.
//   B-chunk c is 16 KB starting at c*16384; staged linearly into LDS.
// Also M = lora_A @ lora_B ([2][120]).
// ---------------------------------------------------------------------------
__global__ __launch_bounds__(256)
void k0_pack(const float* __restrict__ We1,
             const float* __restrict__ lA,
             const float* __restrict__ lB,
             unsigned short* __restrict__ wsw,
             float* __restrict__ wsM) {
  if (blockIdx.x == 128) {
    int t = threadIdx.x;
    if (t < 2 * VHEADS * PDIM) {
      int d  = t / (VHEADS * PDIM);
      int vp = t - d * (VHEADS * PDIM);
      float s = 0.f;
#pragma unroll
      for (int r = 0; r < RLORA; ++r)
        s = fmaf(lA[d * RLORA + r], lB[r * (VHEADS * PDIM) + vp], s);
      wsM[t] = s;  // layout [d][vp]
    }
    return;
  }
  int t    = blockIdx.x * 256 + threadIdx.x;  // 0..32767
  int lane = t & 63;
  int blk  = t >> 6;                          // 0..511
  int ks   = blk & 1;
  int nt   = (blk >> 1) & 7;
  int c    = blk >> 4;
  int n    = nt * 16 + (lane & 15);
  int kb   = c * 64 + ks * 32 + (lane >> 4) * 8;

  unsigned int u[4];
#pragma unroll
  for (int q = 0; q < 4; ++q) {
    float f0 = We1[(size_t)(kb + 2 * q + 0) * NDIM + n];
    float f1 = We1[(size_t)(kb + 2 * q + 1) * NDIM + n];
    __hip_bfloat16 h0 = __float2bfloat16(f0);
    __hip_bfloat16 h1 = __float2bfloat16(f1);
    u[q] = (unsigned int)*reinterpret_cast<unsigned short*>(&h0) |
           ((unsigned int)*reinterpret_cast<unsigned short*>(&h1) << 16);
  }
  *reinterpret_cast<u32x4*>(wsw + (size_t)t * 8) = u32x4{u[0], u[1], u[2], u[3]};
}

// ---------------------------------------------------------------------------
// k1: fused encoder + heads.  Round-5 structure (dual global_load_lds DMA,
// double-buffered, 4 waves x 16 rows, full K) with a T4 counted-vmcnt loop:
// NEVER drain vmcnt to 0 in steady state.  Prologue stages chunks 0 and 1
// (16 loads/thread in flight); each iter: vmcnt(8) -> s_barrier ->
// COMPUTE(c) -> s_barrier -> STAGE(c+2) into the buffer just read.
//   A: f32 [64][64] chunk, LINEAR DMA dest, source granule pre-XOR-swizzled
//      (granule s of row r holds global granule s^(r&7)); reader un-XORs.
//   B: fragment-packed bf16 chunk (16 KB), linear dest, lane*16 reads.
//   Epilogue: be1/relu/We2/be2 -> z (shfl reduce), z bcast via LDS,
//   fused heads (head v = i*4 + wave, row = lane).
// ---------------------------------------------------------------------------
__global__ __launch_bounds__(256, 2)
void k1_fused(const float* __restrict__ x,
              const unsigned short* __restrict__ wp,
              const float* __restrict__ be1,
              const float* __restrict__ We2,
              const float* __restrict__ be2,
              const float* __restrict__ W1,
              const float* __restrict__ b1,
              const float* __restrict__ W2,
              const float* __restrict__ b2,
              const float* __restrict__ M,
              float* __restrict__ out,
              float* __restrict__ zout) {
  __shared__ char ldsA[2][16384] __attribute__((aligned(16)));
  __shared__ char ldsB[2][16384] __attribute__((aligned(16)));
  __shared__ float zsh[64][2];

  const int tid  = threadIdx.x;
  const int lane = tid & 63;
  const int wv   = tid >> 6;   // 0..3
  const int l15  = lane & 15;
  const int kgrp = lane >> 4;  // 0..3
  const int blk  = blockIdx.x;

  // A staging: instr q stages row wv*16 + q*4 + (lane>>4); dest granule
  // (lane&15) holds source granule (lane&15)^(row&7).
  const int arow_off = wv * 16 + (lane >> 4);        // + q*4
  const char* bsrc = (const char*)wp + lane * 16;    // + c*16384 + (wv*4+q)*1024

  f32x4 acc[8];
#pragma unroll
  for (int i = 0; i < 8; ++i) acc[i] = f32x4{0.f, 0.f, 0.f, 0.f};

  auto STAGE = [&](int b, int c) {
#pragma unroll
    for (int q = 0; q < 4; ++q) {
      int row = arow_off + q * 4;
      const float* asrc = x + ((size_t)(blk * 64 + row) * KDIM + c * BK
                               + (((l15 ^ (row & 7)) << 2)));
      gload_lds16(asrc, &ldsA[b][(wv * 4 + q) * 1024]);
    }
#pragma unroll
    for (int q = 0; q < 4; ++q) {
      gload_lds16(bsrc + (size_t)c * 16384 + (wv * 4 + q) * 1024,
                  &ldsB[b][(wv * 4 + q) * 1024]);
    }
  };

  auto COMPUTE = [&](int b) {
    const int row = wv * 16 + l15;
    const char* abase = &ldsA[b][row * 256];
    const int rx = (row & 7) << 4;
    f32x4 A0 = *(const f32x4*)(abase + (((kgrp * 2 + 0) << 4) ^ rx));
    f32x4 A1 = *(const f32x4*)(abase + (((kgrp * 2 + 1) << 4) ^ rx));
    f32x4 A2 = *(const f32x4*)(abase + 128 + (((kgrp * 2 + 0) << 4) ^ rx));
    f32x4 A3 = *(const f32x4*)(abase + 128 + (((kgrp * 2 + 1) << 4) ^ rx));
    FragU a0, a1;
    a0.u = u32x4{cvt_pk_bf16(A0.x, A0.y), cvt_pk_bf16(A0.z, A0.w),
                 cvt_pk_bf16(A1.x, A1.y), cvt_pk_bf16(A1.z, A1.w)};
    a1.u = u32x4{cvt_pk_bf16(A2.x, A2.y), cvt_pk_bf16(A2.z, A2.w),
                 cvt_pk_bf16(A3.x, A3.y), cvt_pk_bf16(A3.z, A3.w)};
    const char* bbase = &ldsB[b][lane * 16];
#pragma unroll
    for (int nt = 0; nt < 8; ++nt) {
      FragU b0, b1;
      b0.u = *(const u32x4*)(bbase + (nt * 2 + 0) * 1024);
      b1.u = *(const u32x4*)(bbase + (nt * 2 + 1) * 1024);
      acc[nt] = __builtin_amdgcn_mfma_f32_16x16x32_bf16(a0.b, b0.b, acc[nt], 0, 0, 0);
      acc[nt] = __builtin_amdgcn_mfma_f32_16x16x32_bf16(a1.b, b1.b, acc[nt], 0, 0, 0);
    }
  };

  // prologue: two chunks in flight (16 loads/thread), no drain
  STAGE(0, 0);
  STAGE(1, 1);

#pragma unroll 1
  for (int c = 0; c < NCHUNK; ++c) {
    int b = c & 1;
    // chunk c's 8 loads are the oldest; chunk c+1's 8 may stay in flight
    if (c + 1 < NCHUNK) {
      asm volatile("s_waitcnt vmcnt(8)" ::: "memory");
    } else {
      asm volatile("s_waitcnt vmcnt(0)" ::: "memory");
    }
    __builtin_amdgcn_sched_barrier(0);
    __builtin_amdgcn_s_barrier();          // all waves: buf b fully landed
    COMPUTE(b);
    __builtin_amdgcn_s_barrier();          // all waves done reading buf b
    __builtin_amdgcn_sched_barrier(0);
    if (c + 2 < NCHUNK) STAGE(b, c + 2);   // overwrite buf b; in flight
  }

  // ---- epilogue: +be1, relu, @We2, +be2 -> z rows (blk*64 + wv*16 ..+15)
  float part[4][2];
#pragma unroll
  for (int j = 0; j < 4; ++j) { part[j][0] = 0.f; part[j][1] = 0.f; }
#pragma unroll
  for (int nt = 0; nt < 8; ++nt) {
    int col = nt * 16 + l15;
    float bb = be1[col];
    float w0 = We2[col * 2 + 0];
    float w1 = We2[col * 2 + 1];
#pragma unroll
    for (int j = 0; j < 4; ++j) {
      float h = acc[nt][j] + bb;
      h = h > 0.f ? h : 0.f;
      part[j][0] = fmaf(h, w0, part[j][0]);
      part[j][1] = fmaf(h, w1, part[j][1]);
    }
  }
#pragma unroll
  for (int m = 1; m < 16; m <<= 1) {
#pragma unroll
    for (int j = 0; j < 4; ++j) {
      part[j][0] += __shfl_xor(part[j][0], m, 64);
      part[j][1] += __shfl_xor(part[j][1], m, 64);
    }
  }
  if (l15 == 0) {
    float bz0 = be2[0], bz1 = be2[1];
#pragma unroll
    for (int j = 0; j < 4; ++j) {
      int rl = wv * 16 + kgrp * 4 + j;   // C row = (lane>>4)*4 + reg
      float zz0 = part[j][0] + bz0;
      float zz1 = part[j][1] + bz1;
      zsh[rl][0] = zz0;
      zsh[rl][1] = zz1;
      f32x2 zz = {zz0, zz1};
      *(f32x2*)(zout + (size_t)(blk * 64 + rl) * 2) = zz;
    }
  }
  __syncthreads();

  // ---- heads: row = lane, head v = i*4 + wv (wave-uniform -> scalar weights)
  const int wvu = __builtin_amdgcn_readfirstlane(wv);
  float z0 = zsh[lane][0];
  float z1 = zsh[lane][1];
  float* orow = out + (size_t)(blk * 64 + lane) * (VHEADS * PDIM);

#pragma unroll 1
  for (int i = 0; i < 5; ++i) {
    int v = i * 4 + wvu;
    const float* w1a = W1 + (size_t)(v * 2 + 0) * NDIM;
    const float* w1b = W1 + (size_t)(v * 2 + 1) * NDIM;
    const float* bb1 = b1 + (size_t)v * NDIM;
    const float* w2  = W2 + (size_t)v * NDIM * PDIM;

    float p[6] = {0.f, 0.f, 0.f, 0.f, 0.f, 0.f};
#pragma unroll 4
    for (int h = 0; h < NDIM; ++h) {
      float hv = fmaf(z0, w1a[h], fmaf(z1, w1b[h], bb1[h]));
      hv = hv > 0.f ? hv : 0.f;
#pragma unroll
      for (int j = 0; j < 6; ++j) p[j] = fmaf(hv, w2[h * 6 + j], p[j]);
    }
    float o[6];
#pragma unroll
    for (int j = 0; j < 6; ++j) {
      float t1 = fast_tanh(p[j] + b2[v * PDIM + j]);
      float lo = fmaf(z0, M[v * PDIM + j], z1 * M[VHEADS * PDIM + v * PDIM + j]);
      o[j] = fast_tanh(fmaf(0.15f, lo, t1));
    }
    float* op = orow + v * PDIM;
    f32x2 o01 = {o[0], o[1]};
    f32x2 o23 = {o[2], o[3]};
    f32x2 o45 = {o[4], o[5]};
    __builtin_nontemporal_store(o01, (f32x2*)(op + 0));
    __builtin_nontemporal_store(o23, (f32x2*)(op + 2));
    __builtin_nontemporal_store(o45, (f32x2*)(op + 4));
  }
}

// ---------------------------------------------------------------------------
extern "C" void kernel_launch(void* const* d_in, const int* in_sizes, int n_in,
                              void* d_out, int out_size, void* d_ws, size_t ws_size,
                              hipStream_t stream) {
  const float* x   = (const float*)d_in[0];
  const float* We1 = (const float*)d_in[1];
  const float* be1 = (const float*)d_in[2];
  const float* We2 = (const float*)d_in[3];
  const float* be2 = (const float*)d_in[4];
  const float* W1  = (const float*)d_in[5];
  const float* b1  = (const float*)d_in[6];
  const float* W2  = (const float*)d_in[7];
  const float* b2  = (const float*)d_in[8];
  const float* lA  = (const float*)d_in[9];
  const float* lB  = (const float*)d_in[10];

  float* out  = (float*)d_out;
  float* zout = out + OUT_ELEMS;                       // second tuple output
  unsigned short* wsw = (unsigned short*)d_ws;         // 512 KB bf16 W pack
  float* wsM = (float*)((char*)d_ws + WS_W_BYTES);     // 240 floats

  hipLaunchKernelGGL(k0_pack, dim3(129), dim3(256), 0, stream,
                     We1, lA, lB, wsw, wsM);
  hipLaunchKernelGGL(k1_fused, dim3(BDIM / 64), dim3(256), 0, stream,
                     x, wsw, be1, We2, be2, W1, b1, W2, b2, wsM, out, zout);
}